// Round 4
// baseline (29.267 us; speedup 1.0000x reference)
//
#include <hip/hip_runtime.h>
#include <math.h>

#define HALF 5
#define BLOCK 256
#define TILE 2048            // outputs per block
#define SLDS (TILE + 16)     // staged floats: in[g0-8 .. g0+TILE+8)

typedef float floatx4 __attribute__((ext_vector_type(4)));

__global__ __launch_bounds__(BLOCK) void dilation1d_kernel(
    const float* __restrict__ in, const float* __restrict__ scale_p,
    float* __restrict__ out, int N)
{
    __shared__ float s[SLDS];
    const float inv4s = 1.0f / (4.0f * scale_p[0]);
    // h[d] = -(d^2)/(4*scale); symmetric; h[0] = -0.0 (exact identity add)
    float h[HALF + 1];
    #pragma unroll
    for (int d = 0; d <= HALF; ++d) h[d] = -(float)(d * d) * inv4s;

    const int t  = threadIdx.x;
    const int g0 = blockIdx.x * TILE;

    // Stage: s[j] = in[g0 - 8 + j], -inf when out of range.
    // Lane-consecutive 4B loads -> fully coalesced; ds_write conflict-free.
    #pragma unroll
    for (int k = 0; k < 8; ++k) {
        const int j = t + k * BLOCK;
        const int idx = g0 - 8 + j;
        s[j] = ((unsigned)idx < (unsigned)N) ? in[idx] : -INFINITY;
    }
    {   // tail: 16 floats
        const int j = t + 8 * BLOCK;
        if (j < SLDS) {
            const int idx = g0 - 8 + j;
            s[j] = ((unsigned)idx < (unsigned)N) ? in[idx] : -INFINITY;
        }
    }
    __syncthreads();

    // Slot layout: thread t computes outputs [g0+4t, +4) and [g0+1024+4t, +4).
    // LDS reads: 5x ds_read_b128, lane-consecutive -> conflict-free.
    // Stores: one float4 per group, lane-consecutive -> perfectly coalesced.
    #pragma unroll
    for (int grp = 0; grp < 2; ++grp) {
        const int p = 4 * t + grp * (TILE / 2);   // local output base
        float w[20];                               // s[p .. p+20)
        const floatx4* ps = (const floatx4*)(s + p);
        #pragma unroll
        for (int v = 0; v < 5; ++v) {
            floatx4 f = ps[v];
            w[4*v+0] = f.x; w[4*v+1] = f.y; w[4*v+2] = f.z; w[4*v+3] = f.w;
        }
        // out[g0+p+u] = max_d ( max(x[i-d], x[i+d]) + h[d] ), center tap free.
        // Bit-exact vs reference: RN monotone => max(a,b)+h == max(a+h,b+h).
        float o[4];
        #pragma unroll
        for (int u = 0; u < 4; ++u) {
            float m = w[u + 8];                    // s-idx p+u+8 == input g0+p+u
            #pragma unroll
            for (int d = 1; d <= HALF; ++d)
                m = fmaxf(m, fmaxf(w[u + 8 - d], w[u + 8 + d]) + h[d]);
            o[u] = m;
        }
        const int go = g0 + p;
        if (go + 4 <= N) {
            floatx4 v = {o[0], o[1], o[2], o[3]};
            *(floatx4*)(out + go) = v;
        } else {
            #pragma unroll
            for (int u = 0; u < 4; ++u)
                if (go + u < N) out[go + u] = o[u];
        }
    }
}

extern "C" void kernel_launch(void* const* d_in, const int* in_sizes, int n_in,
                              void* d_out, int out_size, void* d_ws, size_t ws_size,
                              hipStream_t stream) {
    const float* in      = (const float*)d_in[0];
    const float* scale_p = (const float*)d_in[1];
    float* out           = (float*)d_out;
    const int N = in_sizes[0];
    const int grid = (N + TILE - 1) / TILE;
    hipLaunchKernelGGL(dilation1d_kernel, dim3(grid), dim3(BLOCK), 0, stream,
                       in, scale_p, out, N);
}